// Round 8
// baseline (20862.070 us; speedup 1.0000x reference)
//
#include <hip/hip_runtime.h>

#define N_NODES 50000
#define N_EDGES 800000
#define D 128
#define ED 64
#define NLAYERS 3

// ---------------- prep kernels (build dst-sorted CSR each call) ----------------

__global__ void hist_kernel(const int* __restrict__ dst, int* __restrict__ deg) {
    int e = blockIdx.x * blockDim.x + threadIdx.x;
    if (e < N_EDGES) atomicAdd(&deg[dst[e]], 1);
}

__global__ void scan_kernel(int* __restrict__ deg_cursor, int* __restrict__ row_start) {
    __shared__ int part[1024];
    const int t = threadIdx.x;
    const int CH = (N_NODES + 1023) / 1024;  // 49
    int a = t * CH;
    int b = min(a + CH, N_NODES);
    int s = 0;
    for (int i = a; i < b; ++i) s += deg_cursor[i];
    part[t] = s;
    __syncthreads();
    for (int off = 1; off < 1024; off <<= 1) {
        int v = (t >= off) ? part[t - off] : 0;
        __syncthreads();
        part[t] += v;
        __syncthreads();
    }
    int base = (t == 0) ? 0 : part[t - 1];
    for (int i = a; i < b; ++i) {
        int d = deg_cursor[i];
        row_start[i] = base;
        deg_cursor[i] = base;
        base += d;
    }
    if (t == 1023) row_start[N_NODES] = part[1023];
}

__global__ void scatter_kernel(const int* __restrict__ dst, int* __restrict__ cursor,
                               int* __restrict__ perm) {
    int e = blockIdx.x * blockDim.x + threadIdx.x;
    if (e < N_EDGES) {
        int pos = atomicAdd(&cursor[dst[e]], 1);
        perm[pos] = e;
    }
}

// physically reorder edge_attr/src/dst into dst-sorted order (once per call).
__global__ void reorder_kernel(const float4* __restrict__ ea, const int* __restrict__ perm,
                               const int* __restrict__ src, const int* __restrict__ dst,
                               float4* __restrict__ ea_d, int* __restrict__ srcd,
                               int* __restrict__ dstd) {
    int idx = blockIdx.x * blockDim.x + threadIdx.x;
    int i = idx >> 2, q = idx & 3;
    if (i < N_EDGES) {
        int pe = perm[i];
        const float4* srow = ea + (size_t)pe * (ED / 4);
        float4* drow = ea_d + (size_t)i * (ED / 4);
        #pragma unroll
        for (int j = 0; j < 4; ++j) drow[q * 4 + j] = srow[q * 4 + j];
        if (q == 0) { srcd[i] = src[pe]; dstd[i] = dst[pe]; }
    }
}

// ---------------- edge pass: EB-batched segmented streaming ----------------
// Weight residency in VGPRs is unachievable (r5/r6/r7: allocator demotes or
// scratch-spills 64-element per-lane arrays). Instead amortize: load each We
// float2 once per EB=8 edges (8 weight-loads/edge, not 64). ea rows are
// wave-uniform loads (scalar path); x[src] is a per-lane float2 gather.
// dst-sorted stream + register segmented-scan commit => no LDS, no barriers,
// no atomics, no per-node tail.

template<int EB>
__device__ __forceinline__ void process_group(
    int e0, const int* __restrict__ srcA, const int* __restrict__ dstA,
    const int* __restrict__ permN,
    const float* __restrict__ x, const float* __restrict__ eaA,
    const float* __restrict__ We, int c0, float2 be2,
    float2& acc, int& cur, float* __restrict__ hpre)
{
    int pes[EB], srcs[EB], dsts[EB];
    #pragma unroll
    for (int j = 0; j < EB; ++j) {
        pes[j]  = permN ? permN[e0 + j] : (e0 + j);
        srcs[j] = srcA[pes[j]];
        dsts[j] = dstA[pes[j]];
    }
    float2 xs[EB];
    #pragma unroll
    for (int j = 0; j < EB; ++j)
        xs[j] = *(const float2*)&x[(size_t)srcs[j] * D + c0];

    float2 s[EB];
    #pragma unroll
    for (int j = 0; j < EB; ++j) s[j] = make_float2(0.f, 0.f);

    #pragma unroll
    for (int q = 0; q < 16; ++q) {
        float2 w0 = *(const float2*)&We[(q * 4 + 0) * D + c0];
        float2 w1 = *(const float2*)&We[(q * 4 + 1) * D + c0];
        float2 w2 = *(const float2*)&We[(q * 4 + 2) * D + c0];
        float2 w3 = *(const float2*)&We[(q * 4 + 3) * D + c0];
        #pragma unroll
        for (int j = 0; j < EB; ++j) {
            float4 a = *(const float4*)&eaA[(size_t)pes[j] * ED + q * 4];
            s[j].x = fmaf(a.x, w0.x, s[j].x); s[j].y = fmaf(a.x, w0.y, s[j].y);
            s[j].x = fmaf(a.y, w1.x, s[j].x); s[j].y = fmaf(a.y, w1.y, s[j].y);
            s[j].x = fmaf(a.z, w2.x, s[j].x); s[j].y = fmaf(a.z, w2.y, s[j].y);
            s[j].x = fmaf(a.w, w3.x, s[j].x); s[j].y = fmaf(a.w, w3.y, s[j].y);
        }
    }
    #pragma unroll
    for (int j = 0; j < EB; ++j) {
        float mx = fmaxf(xs[j].x + s[j].x + be2.x, 0.f);
        float my = fmaxf(xs[j].y + s[j].y + be2.y, 0.f);
        if (dsts[j] != cur) {                       // uniform branch (scalar)
            *(float2*)&hpre[(size_t)cur * D + c0] = acc;
            cur = dsts[j];
            acc = *(const float2*)&x[(size_t)cur * D + c0];
        }
        acc.x += mx; acc.y += my;
    }
}

__global__ __launch_bounds__(256, 4)
void edge_agg_kernel(const float* __restrict__ x,
                     const float* __restrict__ eaA,   // [E][ED] (dst-sorted if direct)
                     const int* __restrict__ srcA,
                     const int* __restrict__ dstA,
                     const int* __restrict__ permN,   // nullptr => direct (sorted) mode
                     const int* __restrict__ row_start,
                     const float* __restrict__ We,    // [ED][D]
                     const float* __restrict__ be,    // [D]
                     float* __restrict__ hpre,        // [N][D]
                     int nranges, int epw)
{
    const int t    = threadIdx.x;
    const int lane = t & 63;
    const int rid  = (blockIdx.x * 256 + t) >> 6;    // 1 wave per range
    if (rid >= nranges) return;
    const int c0 = lane * 2;
    const float2 be2 = *(const float2*)&be[c0];

    // node-aligned range via binary search on row_start
    int lo_t = min(rid * epw, N_EDGES);
    int hi_t = min((rid + 1) * epw, N_EDGES);
    int n_lo, n_hi;
    { int a = 0, b = N_NODES;
      while (a < b) { int m = (a + b) >> 1; if (row_start[m] < lo_t) a = m + 1; else b = m; }
      n_lo = a; }
    if (rid == nranges - 1) {
        n_hi = N_NODES;
    } else {
        int a = 0, b = N_NODES;
        while (a < b) { int m = (a + b) >> 1; if (row_start[m] < hi_t) a = m + 1; else b = m; }
        n_hi = a;
    }

    const int ebeg = row_start[n_lo];
    const int eend = row_start[n_hi];

    if (ebeg < eend) {
        int cur = dstA[permN ? permN[ebeg] : ebeg];
        float2 acc = *(const float2*)&x[(size_t)cur * D + c0];
        int e = ebeg;
        for (; e + 8 <= eend; e += 8) {
            process_group<8>(e, srcA, dstA, permN, x, eaA, We, c0, be2, acc, cur, hpre);
            asm volatile("" ::: "memory");   // block LICM re-hoisting the We loads
        }
        if (e + 4 <= eend) {
            process_group<4>(e, srcA, dstA, permN, x, eaA, We, c0, be2, acc, cur, hpre);
            e += 4;
        }
        for (; e < eend; ++e)
            process_group<1>(e, srcA, dstA, permN, x, eaA, We, c0, be2, acc, cur, hpre);
        *(float2*)&hpre[(size_t)cur * D + c0] = acc;   // final segment
    }

    // degree-0 nodes in range: hpre = x
    for (int n = n_lo; n < n_hi; ++n)
        if (row_start[n] == row_start[n + 1])
            *(float2*)&hpre[(size_t)n * D + c0] = *(const float2*)&x[(size_t)n * D + c0];
}

// ---------------- MLP GEMM: out = [relu](in @ W + b) ----------------

__global__ __launch_bounds__(256, 3)
void mlp_kernel(const float* __restrict__ in,   // [N][D]
                const float* __restrict__ W,    // [D][D]
                const float* __restrict__ bias, // [D]
                float* __restrict__ out,        // [N][D]
                int do_relu)
{
    __shared__ float sWh[64][D];     // 32 KB : W[k0+kl][c]
    __shared__ float sIn[64][68];    // 17.4 KB : input tile transposed [kl][row]

    const int t  = threadIdx.x;
    const int n0 = blockIdx.x * 64;
    const int r0 = (t >> 5) * 8;
    const int c0 = (t & 31) * 4;

    float acc[8][4];
    #pragma unroll
    for (int e = 0; e < 8; ++e)
        #pragma unroll
        for (int j = 0; j < 4; ++j) acc[e][j] = 0.f;

    for (int k0 = 0; k0 < D; k0 += 64) {
        __syncthreads();
        {
            const float4* w4 = (const float4*)W;
            #pragma unroll
            for (int i = 0; i < 8; ++i) {
                int idx = t + i * 256;
                int kl = idx >> 5, c4 = idx & 31;
                *(float4*)&sWh[kl][c4 * 4] = w4[(size_t)(k0 + kl) * 32 + c4];
            }
        }
        {
            int r = t & 63, prt = t >> 6;
            int gr = n0 + r;
            #pragma unroll
            for (int q = 0; q < 4; ++q) {
                float4 v = make_float4(0.f, 0.f, 0.f, 0.f);
                if (gr < N_NODES) v = ((const float4*)&in[(size_t)gr * D])[(k0 >> 2) + prt * 4 + q];
                int kl = prt * 16 + q * 4;
                sIn[kl + 0][r] = v.x;
                sIn[kl + 1][r] = v.y;
                sIn[kl + 2][r] = v.z;
                sIn[kl + 3][r] = v.w;
            }
        }
        __syncthreads();

        #pragma unroll 8
        for (int kl = 0; kl < 64; ++kl) {
            float4 b4 = *(const float4*)&sWh[kl][c0];
            float4 a0 = *(const float4*)&sIn[kl][r0];
            float4 a1 = *(const float4*)&sIn[kl][r0 + 4];
            float av[8] = {a0.x, a0.y, a0.z, a0.w, a1.x, a1.y, a1.z, a1.w};
            float bv[4] = {b4.x, b4.y, b4.z, b4.w};
            #pragma unroll
            for (int e = 0; e < 8; ++e)
                #pragma unroll
                for (int j = 0; j < 4; ++j)
                    acc[e][j] = fmaf(av[e], bv[j], acc[e][j]);
        }
    }

    float4 bb = *(const float4*)&bias[c0];
    #pragma unroll
    for (int e = 0; e < 8; ++e) {
        int gr = n0 + r0 + e;
        if (gr < N_NODES) {
            float4 o;
            o.x = acc[e][0] + bb.x;
            o.y = acc[e][1] + bb.y;
            o.z = acc[e][2] + bb.z;
            o.w = acc[e][3] + bb.w;
            if (do_relu) {
                o.x = fmaxf(o.x, 0.f); o.y = fmaxf(o.y, 0.f);
                o.z = fmaxf(o.z, 0.f); o.w = fmaxf(o.w, 0.f);
            }
            *(float4*)&out[(size_t)gr * D + c0] = o;
        }
    }
}

// ---------------- host ----------------

extern "C" void kernel_launch(void* const* d_in, const int* in_sizes, int n_in,
                              void* d_out, int out_size, void* d_ws, size_t ws_size,
                              hipStream_t stream) {
    const float* x  = (const float*)d_in[0];
    const int*   ei = (const int*)d_in[1];
    const float* ea = (const float*)d_in[2];
    const float* We = (const float*)d_in[3];
    const float* be = (const float*)d_in[4];
    const float* W1 = (const float*)d_in[5];
    const float* b1 = (const float*)d_in[6];
    const float* W2 = (const float*)d_in[7];
    const float* b2 = (const float*)d_in[8];
    float* out = (float*)d_out;

    const int* src = ei;
    const int* dst = ei + N_EDGES;

    char* ws = (char*)d_ws;
    size_t off = 0;
    auto alloc = [&](size_t bytes) -> char* {
        char* p = ws + off;
        off = (off + bytes + 255) & ~(size_t)255;
        return p;
    };
    float* P         = (float*)alloc((size_t)N_NODES * D * sizeof(float));
    float* T         = (float*)alloc((size_t)N_NODES * D * sizeof(float));
    float* H         = (float*)alloc((size_t)N_NODES * D * sizeof(float));
    int*   perm      = (int*)alloc((size_t)N_EDGES * sizeof(int));
    int*   row_start = (int*)alloc((size_t)(N_NODES + 1) * sizeof(int));
    int*   cursor    = (int*)alloc((size_t)N_NODES * sizeof(int));
    // big reordered buffers last; fall back to indirect mode if ws too small
    int*   srcd = (int*)alloc((size_t)N_EDGES * sizeof(int));
    int*   dstd = (int*)alloc((size_t)N_EDGES * sizeof(int));
    float* ea_d = (float*)alloc((size_t)N_EDGES * ED * sizeof(float));
    const bool direct = (off <= ws_size);
    (void)in_sizes; (void)n_in; (void)out_size;

    // build dst-sorted CSR (deterministic structure; runs every call)
    hipMemsetAsync(cursor, 0, N_NODES * sizeof(int), stream);
    hist_kernel<<<(N_EDGES + 255) / 256, 256, 0, stream>>>(dst, cursor);
    scan_kernel<<<1, 1024, 0, stream>>>(cursor, row_start);
    scatter_kernel<<<(N_EDGES + 255) / 256, 256, 0, stream>>>(dst, cursor, perm);

    const float* eaA = ea;
    const int *srcA = src, *dstA = dst, *permN = perm;
    if (direct) {
        reorder_kernel<<<(N_EDGES * 4 + 255) / 256, 256, 0, stream>>>(
            (const float4*)ea, perm, src, dst, (float4*)ea_d, srcd, dstd);
        eaA = ea_d; srcA = srcd; dstA = dstd; permN = nullptr;
    }

    // 4096 ranges x 1 wave = 16 waves/CU at (256,4)
    const int nranges = 4096;
    const int eblocks = nranges / 4;                        // 4 waves per block
    const int epw     = (N_EDGES + nranges - 1) / nranges;  // 196
    const int mgrid   = (N_NODES + 63) / 64;                // 782

    const float* X = x;
    for (int l = 0; l < NLAYERS; ++l) {
        edge_agg_kernel<<<eblocks, 256, 0, stream>>>(X, eaA, srcA, dstA, permN, row_start,
            We + (size_t)l * ED * D, be + (size_t)l * D, P, nranges, epw);
        mlp_kernel<<<mgrid, 256, 0, stream>>>(P, W1 + (size_t)l * D * D, b1 + (size_t)l * D, T, 1);
        float* ob = (l < NLAYERS - 1) ? H : out;
        mlp_kernel<<<mgrid, 256, 0, stream>>>(T, W2 + (size_t)l * D * D, b2 + (size_t)l * D, ob,
                                              (l < NLAYERS - 1) ? 1 : 0);
        X = H;
    }
}

// Round 9
// 1719.767 us; speedup vs baseline: 12.1308x; 12.1308x over previous
//
#include <hip/hip_runtime.h>

#define N_NODES 50000
#define N_EDGES 800000
#define D 128
#define ED 64
#define NLAYERS 3

typedef __attribute__((ext_vector_type(8))) short s16x8;
typedef __attribute__((ext_vector_type(4))) float f32x4;
#define MFMA16 __builtin_amdgcn_mfma_f32_16x16x32_bf16

__device__ __forceinline__ unsigned short f2bf(float f) {
    unsigned int u = __float_as_uint(f);
    unsigned int r = (u + 0x7FFFu + ((u >> 16) & 1u)) >> 16;
    return (unsigned short)r;
}
__device__ __forceinline__ float bf2f(unsigned short h) {
    return __uint_as_float(((unsigned int)h) << 16);
}

// ---------------- prep kernels ----------------

__global__ void hist_kernel(const int* __restrict__ dst, int* __restrict__ deg) {
    int e = blockIdx.x * blockDim.x + threadIdx.x;
    if (e < N_EDGES) atomicAdd(&deg[dst[e]], 1);
}

__global__ void scan_kernel(int* __restrict__ deg_cursor, int* __restrict__ row_start) {
    __shared__ int part[1024];
    const int t = threadIdx.x;
    const int CH = (N_NODES + 1023) / 1024;  // 49
    int a = t * CH;
    int b = min(a + CH, N_NODES);
    int s = 0;
    for (int i = a; i < b; ++i) s += deg_cursor[i];
    part[t] = s;
    __syncthreads();
    for (int off = 1; off < 1024; off <<= 1) {
        int v = (t >= off) ? part[t - off] : 0;
        __syncthreads();
        part[t] += v;
        __syncthreads();
    }
    int base = (t == 0) ? 0 : part[t - 1];
    for (int i = a; i < b; ++i) {
        int d = deg_cursor[i];
        row_start[i] = base;
        deg_cursor[i] = base;
        base += d;
    }
    if (t == 1023) row_start[N_NODES] = part[1023];
}

__global__ void scatter_kernel(const int* __restrict__ dst, int* __restrict__ cursor,
                               int* __restrict__ perm) {
    int e = blockIdx.x * blockDim.x + threadIdx.x;
    if (e < N_EDGES) {
        int pos = atomicAdd(&cursor[dst[e]], 1);
        perm[pos] = e;
    }
}

// reorder src (always) and optionally edge_attr into dst-sorted order
__global__ void reorder_kernel(const float4* __restrict__ ea, const int* __restrict__ perm,
                               const int* __restrict__ src,
                               float4* __restrict__ ea_d, int* __restrict__ srcd) {
    int idx = blockIdx.x * blockDim.x + threadIdx.x;
    int i = idx >> 2, q = idx & 3;
    if (i < N_EDGES) {
        int pe = perm[i];
        if (ea_d) {
            const float4* srow = ea + (size_t)pe * (ED / 4);
            float4* drow = ea_d + (size_t)i * (ED / 4);
            #pragma unroll
            for (int j = 0; j < 4; ++j) drow[q * 4 + j] = srow[q * 4 + j];
        }
        if (q == 0) srcd[i] = src[pe];
    }
}

// We[L][64][128] -> transposed bf16 hi/lo WT[L][128][64]
__global__ void wconv_kernel(const float* __restrict__ We,
                             unsigned short* __restrict__ WThi,
                             unsigned short* __restrict__ WTlo) {
    int idx = blockIdx.x * 256 + threadIdx.x;
    if (idx < NLAYERS * ED * D) {
        int l = idx / (ED * D);
        int rem = idx % (ED * D);
        int k = rem / D, c = rem % D;
        float f = We[idx];
        unsigned short h = f2bf(f);
        unsigned short lo = f2bf(f - bf2f(h));
        int o = (l * D + c) * ED + k;
        WThi[o] = h; WTlo[o] = lo;
    }
}

// ---------------- edge GEMM (MFMA): msg[e] = ea_d[e] @ We + be ----------------
// 128 edges/block, 4 waves; wave w owns rows [32w,32w+32). A staged in LDS as
// bf16 hi/lo, rows padded to 72 ushorts (stride 9*16B rotates bank slots ->
// <=2-way conflicts, free). B (WeT bf16) read per-frag from global (16KB,
// L1-resident). fp32 ~= hi*hi + hi*lo + lo*hi (3 MFMA, rel err ~1e-5).
// MSGF: 1 = fp32 msg, 0 = bf16 msg. permN != nullptr => gather ea via perm.

template<int MSGF>
__global__ __launch_bounds__(256, 3)
void edge_gemm_kernel(const float* __restrict__ eaA,
                      const int* __restrict__ permN,
                      const unsigned short* __restrict__ WThi,
                      const unsigned short* __restrict__ WTlo,
                      const float* __restrict__ be,
                      float* __restrict__ msgf,
                      unsigned short* __restrict__ msgb)
{
    __shared__ unsigned short sAhi[128 * 72];
    __shared__ unsigned short sAlo[128 * 72];
    const int t = threadIdx.x;
    const int e0 = blockIdx.x * 128;

    // stage: thread t -> edge el = t>>1, k-half (t&1)*32
    {
        const int el = t >> 1, k0 = (t & 1) * 32;
        int ge = e0 + el;
        if (permN) ge = permN[ge];
        const float4* s4 = (const float4*)&eaA[(size_t)ge * ED + k0];
        #pragma unroll
        for (int j = 0; j < 4; ++j) {
            float4 va = s4[j * 2], vb = s4[j * 2 + 1];
            float f[8] = {va.x, va.y, va.z, va.w, vb.x, vb.y, vb.z, vb.w};
            s16x8 vh, vl;
            #pragma unroll
            for (int q = 0; q < 8; ++q) {
                unsigned short h = f2bf(f[q]);
                vh[q] = (short)h;
                vl[q] = (short)f2bf(f[q] - bf2f(h));
            }
            *(s16x8*)&sAhi[el * 72 + k0 + j * 8] = vh;
            *(s16x8*)&sAlo[el * 72 + k0 + j * 8] = vl;
        }
    }
    __syncthreads();

    const int w = t >> 6, l = t & 63;
    const int li = l & 15, lk = l >> 4;
    const int erow0 = w * 32;

    // A-frags: [rowtile r=0,1][kstep s=0,1], hi & lo  (statically indexed)
    s16x8 Ah[2][2], Al[2][2];
    #pragma unroll
    for (int r = 0; r < 2; ++r)
        #pragma unroll
        for (int s = 0; s < 2; ++s) {
            int edge = erow0 + r * 16 + li;
            Ah[r][s] = *(const s16x8*)&sAhi[edge * 72 + s * 32 + lk * 8];
            Al[r][s] = *(const s16x8*)&sAlo[edge * 72 + s * 32 + lk * 8];
        }

    #pragma unroll
    for (int c = 0; c < 8; ++c) {
        const int col = c * 16 + li;
        f32x4 acc0 = {0.f, 0.f, 0.f, 0.f}, acc1 = {0.f, 0.f, 0.f, 0.f};
        #pragma unroll
        for (int s = 0; s < 2; ++s) {
            const s16x8 Bh = *(const s16x8*)&WThi[col * ED + s * 32 + lk * 8];
            const s16x8 Bl = *(const s16x8*)&WTlo[col * ED + s * 32 + lk * 8];
            acc0 = MFMA16(Ah[0][s], Bh, acc0, 0, 0, 0);
            acc1 = MFMA16(Ah[1][s], Bh, acc1, 0, 0, 0);
            acc0 = MFMA16(Ah[0][s], Bl, acc0, 0, 0, 0);
            acc1 = MFMA16(Ah[1][s], Bl, acc1, 0, 0, 0);
            acc0 = MFMA16(Al[0][s], Bh, acc0, 0, 0, 0);
            acc1 = MFMA16(Al[1][s], Bh, acc1, 0, 0, 0);
        }
        const float bias = be[col];
        // D mapping: col = lane&15, row = (lane>>4)*4 + reg  [m89-verified]
        #pragma unroll
        for (int reg = 0; reg < 4; ++reg) {
            size_t r0i = (size_t)(e0 + erow0 + lk * 4 + reg) * D + col;
            size_t r1i = (size_t)(e0 + erow0 + 16 + lk * 4 + reg) * D + col;
            if (MSGF) {
                msgf[r0i] = acc0[reg] + bias;
                msgf[r1i] = acc1[reg] + bias;
            } else {
                msgb[r0i] = f2bf(acc0[reg] + bias);
                msgb[r1i] = f2bf(acc1[reg] + bias);
            }
        }
    }
}

// ---------------- segmented reduce: hpre[n] = x[n] + sum relu(x[src]+msg) ----------------

template<int MSGF>
__global__ __launch_bounds__(256, 4)
void seg_reduce_kernel(const float* __restrict__ x,
                       const float* __restrict__ msgf,
                       const unsigned short* __restrict__ msgb,
                       const int* __restrict__ srcd,
                       const int* __restrict__ row_start,
                       float* __restrict__ hpre,
                       int nranges, int epw)
{
    const int t = threadIdx.x, lane = t & 63;
    const int rid = (blockIdx.x * 256 + t) >> 6;
    if (rid >= nranges) return;
    const int c0 = lane * 2;

    int lo_t = min(rid * epw, N_EDGES);
    int hi_t = min((rid + 1) * epw, N_EDGES);
    int n_lo, n_hi;
    { int a = 0, b = N_NODES;
      while (a < b) { int m = (a + b) >> 1; if (row_start[m] < lo_t) a = m + 1; else b = m; }
      n_lo = a; }
    if (rid == nranges - 1) {
        n_hi = N_NODES;
    } else {
        int a = 0, b = N_NODES;
        while (a < b) { int m = (a + b) >> 1; if (row_start[m] < hi_t) a = m + 1; else b = m; }
        n_hi = a;
    }

    for (int n = n_lo; n < n_hi; ++n) {
        float2 acc = *(const float2*)&x[(size_t)n * D + c0];   // (1+eps)*x, eps=0
        const int ebeg = row_start[n], eend = row_start[n + 1];
        for (int e = ebeg; e < eend; ++e) {
            float2 m;
            if (MSGF) {
                m = *(const float2*)&msgf[(size_t)e * D + c0];
            } else {
                unsigned int u = *(const unsigned int*)&msgb[(size_t)e * D + c0];
                m.x = bf2f((unsigned short)(u & 0xFFFFu));
                m.y = bf2f((unsigned short)(u >> 16));
            }
            float2 xs = *(const float2*)&x[(size_t)srcd[e] * D + c0];
            acc.x += fmaxf(m.x + xs.x, 0.f);
            acc.y += fmaxf(m.y + xs.y, 0.f);
        }
        *(float2*)&hpre[(size_t)n * D + c0] = acc;
    }
}

// ---------------- MLP GEMM: out = [relu](in @ W + b) ----------------

__global__ __launch_bounds__(256, 3)
void mlp_kernel(const float* __restrict__ in,
                const float* __restrict__ W,
                const float* __restrict__ bias,
                float* __restrict__ out,
                int do_relu)
{
    __shared__ float sWh[64][D];
    __shared__ float sIn[64][68];

    const int t  = threadIdx.x;
    const int n0 = blockIdx.x * 64;
    const int r0 = (t >> 5) * 8;
    const int c0 = (t & 31) * 4;

    float acc[8][4];
    #pragma unroll
    for (int e = 0; e < 8; ++e)
        #pragma unroll
        for (int j = 0; j < 4; ++j) acc[e][j] = 0.f;

    for (int k0 = 0; k0 < D; k0 += 64) {
        __syncthreads();
        {
            const float4* w4 = (const float4*)W;
            #pragma unroll
            for (int i = 0; i < 8; ++i) {
                int idx = t + i * 256;
                int kl = idx >> 5, c4 = idx & 31;
                *(float4*)&sWh[kl][c4 * 4] = w4[(size_t)(k0 + kl) * 32 + c4];
            }
        }
        {
            int r = t & 63, prt = t >> 6;
            int gr = n0 + r;
            #pragma unroll
            for (int q = 0; q < 4; ++q) {
                float4 v = make_float4(0.f, 0.f, 0.f, 0.f);
                if (gr < N_NODES) v = ((const float4*)&in[(size_t)gr * D])[(k0 >> 2) + prt * 4 + q];
                int kl = prt * 16 + q * 4;
                sIn[kl + 0][r] = v.x;
                sIn[kl + 1][r] = v.y;
                sIn[kl + 2][r] = v.z;
                sIn[kl + 3][r] = v.w;
            }
        }
        __syncthreads();

        #pragma unroll 8
        for (int kl = 0; kl < 64; ++kl) {
            float4 b4 = *(const float4*)&sWh[kl][c0];
            float4 a0 = *(const float4*)&sIn[kl][r0];
            float4 a1 = *(const float4*)&sIn[kl][r0 + 4];
            float av[8] = {a0.x, a0.y, a0.z, a0.w, a1.x, a1.y, a1.z, a1.w};
            float bv[4] = {b4.x, b4.y, b4.z, b4.w};
            #pragma unroll
            for (int e = 0; e < 8; ++e)
                #pragma unroll
                for (int j = 0; j < 4; ++j)
                    acc[e][j] = fmaf(av[e], bv[j], acc[e][j]);
        }
    }

    float4 bb = *(const float4*)&bias[c0];
    #pragma unroll
    for (int e = 0; e < 8; ++e) {
        int gr = n0 + r0 + e;
        if (gr < N_NODES) {
            float4 o;
            o.x = acc[e][0] + bb.x;
            o.y = acc[e][1] + bb.y;
            o.z = acc[e][2] + bb.z;
            o.w = acc[e][3] + bb.w;
            if (do_relu) {
                o.x = fmaxf(o.x, 0.f); o.y = fmaxf(o.y, 0.f);
                o.z = fmaxf(o.z, 0.f); o.w = fmaxf(o.w, 0.f);
            }
            *(float4*)&out[(size_t)gr * D + c0] = o;
        }
    }
}

// ---------------- host ----------------

extern "C" void kernel_launch(void* const* d_in, const int* in_sizes, int n_in,
                              void* d_out, int out_size, void* d_ws, size_t ws_size,
                              hipStream_t stream) {
    const float* x  = (const float*)d_in[0];
    const int*   ei = (const int*)d_in[1];
    const float* ea = (const float*)d_in[2];
    const float* We = (const float*)d_in[3];
    const float* be = (const float*)d_in[4];
    const float* W1 = (const float*)d_in[5];
    const float* b1 = (const float*)d_in[6];
    const float* W2 = (const float*)d_in[7];
    const float* b2 = (const float*)d_in[8];
    float* out = (float*)d_out;

    const int* src = ei;
    const int* dst = ei + N_EDGES;

    char* ws = (char*)d_ws;
    size_t off = 0;
    auto alloc = [&](size_t bytes) -> char* {
        char* p = ws + off;
        off = (off + bytes + 255) & ~(size_t)255;
        return p;
    };
    float* P          = (float*)alloc((size_t)N_NODES * D * 4);
    float* T          = (float*)alloc((size_t)N_NODES * D * 4);
    float* H          = (float*)alloc((size_t)N_NODES * D * 4);
    int*   perm       = (int*)alloc((size_t)N_EDGES * 4);
    int*   row_start  = (int*)alloc((size_t)(N_NODES + 1) * 4);
    int*   cursor     = (int*)alloc((size_t)N_NODES * 4);
    int*   srcd       = (int*)alloc((size_t)N_EDGES * 4);
    unsigned short* WThi = (unsigned short*)alloc((size_t)NLAYERS * D * ED * 2);
    unsigned short* WTlo = (unsigned short*)alloc((size_t)NLAYERS * D * ED * 2);
    const size_t base_end = off;

    // tier 1: sorted ea + fp32 msg ; tier 2: sorted ea + bf16 msg ; tier 3: indirect + bf16
    float* ea_d = nullptr; float* msgf = nullptr; unsigned short* msgb = nullptr;
    int tier;
    {
        ea_d = (float*)alloc((size_t)N_EDGES * ED * 4);
        msgf = (float*)alloc((size_t)N_EDGES * D * 4);
        if (off <= ws_size) { tier = 1; }
        else {
            off = base_end; msgf = nullptr;
            ea_d = (float*)alloc((size_t)N_EDGES * ED * 4);
            msgb = (unsigned short*)alloc((size_t)N_EDGES * D * 2);
            if (off <= ws_size) { tier = 2; }
            else {
                off = base_end; ea_d = nullptr;
                msgb = (unsigned short*)alloc((size_t)N_EDGES * D * 2);
                tier = 3;
            }
        }
    }
    (void)in_sizes; (void)n_in; (void)out_size;

    // build dst-sorted CSR
    hipMemsetAsync(cursor, 0, N_NODES * 4, stream);
    hist_kernel<<<(N_EDGES + 255) / 256, 256, 0, stream>>>(dst, cursor);
    scan_kernel<<<1, 1024, 0, stream>>>(cursor, row_start);
    scatter_kernel<<<(N_EDGES + 255) / 256, 256, 0, stream>>>(dst, cursor, perm);
    reorder_kernel<<<(N_EDGES * 4 + 255) / 256, 256, 0, stream>>>(
        (const float4*)ea, perm, src, (float4*)ea_d, srcd);
    wconv_kernel<<<(NLAYERS * ED * D + 255) / 256, 256, 0, stream>>>(We, WThi, WTlo);

    const float* eaA  = ea_d ? ea_d : ea;
    const int*   permG = ea_d ? nullptr : perm;

    const int ggrid   = N_EDGES / 128;                      // 6250
    const int nranges = 4096;
    const int rblocks = nranges / 4;
    const int epw     = (N_EDGES + nranges - 1) / nranges;  // 196
    const int mgrid   = (N_NODES + 63) / 64;                // 782

    const float* X = x;
    for (int l = 0; l < NLAYERS; ++l) {
        const unsigned short* wh = WThi + (size_t)l * D * ED;
        const unsigned short* wl = WTlo + (size_t)l * D * ED;
        const float* bel = be + (size_t)l * D;
        if (tier == 1) {
            edge_gemm_kernel<1><<<ggrid, 256, 0, stream>>>(eaA, permG, wh, wl, bel, msgf, nullptr);
            seg_reduce_kernel<1><<<rblocks, 256, 0, stream>>>(X, msgf, nullptr, srcd, row_start, P, nranges, epw);
        } else {
            edge_gemm_kernel<0><<<ggrid, 256, 0, stream>>>(eaA, permG, wh, wl, bel, nullptr, msgb);
            seg_reduce_kernel<0><<<rblocks, 256, 0, stream>>>(X, nullptr, msgb, srcd, row_start, P, nranges, epw);
        }
        mlp_kernel<<<mgrid, 256, 0, stream>>>(P, W1 + (size_t)l * D * D, b1 + (size_t)l * D, T, 1);
        float* ob = (l < NLAYERS - 1) ? H : out;
        mlp_kernel<<<mgrid, 256, 0, stream>>>(T, W2 + (size_t)l * D * D, b2 + (size_t)l * D, ob,
                                              (l < NLAYERS - 1) ? 1 : 0);
        X = H;
    }
}